// Round 1
// baseline (9045.441 us; speedup 1.0000x reference)
//
#include <hip/hip_runtime.h>
#include <cstdint>
#include <cstddef>

#define NN 10000
#define NE 320000
#define LN_EPS 1e-5f

// ---------------- helpers ----------------

__device__ __forceinline__ float wredsum(float v) {
#pragma unroll
  for (int off = 32; off > 0; off >>= 1) v += __shfl_xor(v, off, 64);
  return v;
}

__device__ __forceinline__ unsigned short f2bf(float x) {
  unsigned u = __float_as_uint(x);
  u = u + 0x7FFFu + ((u >> 16) & 1u);
  return (unsigned short)(u >> 16);
}
__device__ __forceinline__ float bf2f(unsigned short s) {
  return __uint_as_float(((unsigned)s) << 16);
}

// ---------------- weight prep: cw[5][64co][64ci][2][2] -> wt[5][256k][64co], k = ci*4+ky*2+kx ----------------

__global__ __launch_bounds__(256) void prep_weights_kernel(const float* __restrict__ cw,
                                                           float* __restrict__ wt) {
  int j = blockIdx.x * 256 + threadIdx.x;
  if (j >= 5 * 16384) return;
  int l = j >> 14;
  int rem = j & 16383;
  int k = rem >> 6;
  int co = rem & 63;
  wt[j] = cw[(size_t)((l << 6) + co) * 256 + k];
}

// ---------------- fused conv stack: crop[N,3,64,64] -> crop_feat[N,64] ----------------
// All convs k=2 s=2 VALID + bias + relu. Streams conv0+conv1 per out1-row, then conv2..5 from LDS.
// LDS im2col convention at every stage: index [k][pixel], k = ci*4 + ky*2 + kx (row-parity, col-parity).

__global__ __launch_bounds__(256) void conv_stack_kernel(
    const float* __restrict__ crop, const float* __restrict__ cw0, const float* __restrict__ cb0,
    const float* __restrict__ wt, const float* __restrict__ cb, float* __restrict__ crop_feat) {
  __shared__ __align__(16) float s0[4864];            // s_in[768] + s_h0[4096]; later aliased: s_o2[4096], s_red[256]
  __shared__ __align__(16) unsigned short s1[16384];  // s_o1 (bf16); later aliased: s_o3 (1024 f) + s_o4 (256 f)

  float* s_in = s0;                      // [3][4][64]
  float* s_h0 = s0 + 768;                // [256][16], col xor-swizzled by (k>>2)&15
  float* s_o2 = s0;                      // [256][16] f (alias, after y-loop)
  float* s_red = s0 + 4096;              // [256] f
  unsigned short* s_o1 = s1;             // [256][64] bf16
  float* s_o3 = (float*)s1;              // [256][4] f (alias after s_o1 consumed)
  float* s_o4 = ((float*)s1) + 1024;     // [256] f

  const int t = threadIdx.x;
  const int n = blockIdx.x;
  const int oc = t & 63, q = t >> 6;   // conv0 mapping
  const int xp = t & 15, cog = t >> 4; // conv1 mapping

  // conv0 weights to registers: cw0[oc][3][2][2]
  float w0r[12];
#pragma unroll
  for (int i = 0; i < 12; i++) w0r[i] = cw0[oc * 12 + i];
  const float b0r = cb0[oc];
  const float* cr = crop + (size_t)n * (3 * 64 * 64);

  for (int y1 = 0; y1 < 16; y1++) {
    // load input rows 4y1..4y1+3 (3ch x 4row x 64col)
#pragma unroll
    for (int rep = 0; rep < 3; rep++) {
      int r = (t >> 6) & 3;
      int col = t & 63;
      s_in[rep * 256 + t] = cr[rep * 4096 + (4 * y1 + r) * 64 + col];
    }
    __syncthreads();

    // conv0: produce out0 rows 2y1,2y1+1 into s_h0 (k = oc*4 + ky*2 + kx, 16 cols x')
    {
      float a0[16];
#pragma unroll
      for (int i = 0; i < 16; i++) a0[i] = b0r;
#pragma unroll
      for (int ci = 0; ci < 3; ci++) {
#pragma unroll
        for (int ROW = 0; ROW < 4; ROW++) {  // ROW = 2*ky + jy
          const int ky = ROW >> 1, jy = ROW & 1;
          const float* rp = s_in + (ci * 4 + ROW) * 64 + 16 * q;
          float v[16];
#pragma unroll
          for (int m = 0; m < 4; m++) ((float4*)v)[m] = ((const float4*)rp)[m];
#pragma unroll
          for (int kx = 0; kx < 2; kx++) {
#pragma unroll
            for (int jx = 0; jx < 2; jx++) {
              const float w = w0r[ci * 4 + jy * 2 + jx];
#pragma unroll
              for (int dx = 0; dx < 4; dx++)
                a0[(ky * 2 + kx) * 4 + dx] += w * v[4 * dx + 2 * kx + jx];
            }
          }
        }
      }
#pragma unroll
      for (int ky = 0; ky < 2; ky++) {
#pragma unroll
        for (int kx = 0; kx < 2; kx++) {
#pragma unroll
          for (int dx = 0; dx < 4; dx++) {
            int k = oc * 4 + ky * 2 + kx;
            int col = (4 * q + dx) ^ (oc & 15);
            s_h0[k * 16 + col] = fmaxf(a0[(ky * 2 + kx) * 4 + dx], 0.f);
          }
        }
      }
    }
    __syncthreads();

    // conv1: out1 row y1 (16 px x 64 ch); thread = (xp, cog of 4 ch)
    {
      float ax = 0.f, ay = 0.f, az = 0.f, aw = 0.f;
      const float* w1p = wt + cog * 4;
#pragma unroll 4
      for (int k = 0; k < 256; k++) {
        float a = s_h0[k * 16 + (xp ^ ((k >> 2) & 15))];
        float w4[4];
        *(float4*)w4 = *(const float4*)(w1p + k * 64);
        ax += a * w4[0];
        ay += a * w4[1];
        az += a * w4[2];
        aw += a * w4[3];
      }
      const int idx2 = (y1 >> 1) * 8 + (xp >> 1);
      const int par = (y1 & 1) * 2 + (xp & 1);
      float r4[4] = {ax, ay, az, aw};
#pragma unroll
      for (int j2 = 0; j2 < 4; j2++) {
        int co = cog * 4 + j2;
        float val = fmaxf(r4[j2] + cb[co], 0.f);
        s_o1[(co * 4 + par) * 64 + idx2] = f2bf(val);
      }
    }
    __syncthreads();
  }

  // conv2: out2[64][8][8]; thread = (p2 = 64 px, cog16 of 16 ch)
  {
    const int p2 = t & 63, cog16 = t >> 6;
    float a2[16];
#pragma unroll
    for (int i = 0; i < 16; i++) a2[i] = 0.f;
    const float* w2p = wt + 16384 + cog16 * 16;
    for (int k = 0; k < 256; k++) {
      float a = bf2f(s_o1[k * 64 + p2]);
      float w16[16];
      const float4* wp = (const float4*)(w2p + k * 64);
      ((float4*)w16)[0] = wp[0];
      ((float4*)w16)[1] = wp[1];
      ((float4*)w16)[2] = wp[2];
      ((float4*)w16)[3] = wp[3];
#pragma unroll
      for (int j2 = 0; j2 < 16; j2++) a2[j2] += a * w16[j2];
    }
    __syncthreads();  // everyone done reading s_o1 before anyone proceeds (s_o3 aliases it)
    const int y2 = p2 >> 3, x2 = p2 & 7;
    const int k3par = (y2 & 1) * 2 + (x2 & 1);
    const int idx3 = (y2 >> 1) * 4 + (x2 >> 1);
#pragma unroll
    for (int j2 = 0; j2 < 16; j2++) {
      int co = cog16 * 16 + j2;
      float val = fmaxf(a2[j2] + cb[64 + co], 0.f);
      s_o2[(co * 4 + k3par) * 16 + idx3] = val;
    }
  }
  __syncthreads();

  // conv3: out3[64][4][4]; thread = (p3 = 16 px, cog4 of 4 ch)
  {
    const int p3 = t & 15, cog4 = t >> 4;
    float a3[4] = {0.f, 0.f, 0.f, 0.f};
    const float* w3p = wt + 2 * 16384 + cog4 * 4;
    for (int k = 0; k < 256; k++) {
      float a = s_o2[k * 16 + p3];
      float w4[4];
      *(float4*)w4 = *(const float4*)(w3p + k * 64);
      a3[0] += a * w4[0];
      a3[1] += a * w4[1];
      a3[2] += a * w4[2];
      a3[3] += a * w4[3];
    }
    const int y3 = p3 >> 2, x3 = p3 & 3;
    const int k4par = (y3 & 1) * 2 + (x3 & 1);
    const int idx4 = (y3 >> 1) * 2 + (x3 >> 1);
#pragma unroll
    for (int j2 = 0; j2 < 4; j2++) {
      int co = cog4 * 4 + j2;
      float val = fmaxf(a3[j2] + cb[128 + co], 0.f);
      s_o3[(co * 4 + k4par) * 4 + idx4] = val;
    }
  }
  __syncthreads();

  // conv4: out4[64][2][2]; thread = (p4 = 4 px, co = 64)
  {
    const int p4 = t & 3, co4 = t >> 2;
    float a4 = 0.f;
    const float* w4p = wt + 3 * 16384 + co4;
    for (int k = 0; k < 256; k++) a4 += s_o3[k * 4 + p4] * w4p[k * 64];
    s_o4[co4 * 4 + p4] = fmaxf(a4 + cb[192 + co4], 0.f);
  }
  __syncthreads();

  // conv5: out5[64]; split K over 4 thread groups then reduce
  {
    const int co = t & 63, ks = t >> 6;
    float p = 0.f;
    const float* w5p = wt + 4 * 16384 + co;
    for (int kk = 0; kk < 64; kk++) {
      int k = ks * 64 + kk;
      p += s_o4[k] * w5p[k * 64];
    }
    s_red[t] = p;
  }
  __syncthreads();
  if (t < 64) {
    float v = s_red[t] + s_red[64 + t] + s_red[128 + t] + s_red[192 + t];
    crop_feat[(size_t)n * 64 + t] = fmaxf(v + cb[256 + t], 0.f);
  }
}

// ---------------- node encoder: LN(relu([x, crop_feat] @ nu_w + nu_b)) ----------------

__global__ __launch_bounds__(256) void encode_nodes_kernel(
    const float* __restrict__ x, const float* __restrict__ cf, const float* __restrict__ nu_w,
    const float* __restrict__ nu_b, const float* __restrict__ nu_g, const float* __restrict__ nu_be,
    float* __restrict__ node) {
  const int lane = threadIdx.x & 63, wv = threadIdx.x >> 6;
  const int n = blockIdx.x * 4 + wv;
  const float* xr = x + (size_t)n * 32;
  const float* crf = cf + (size_t)n * 64;
  float acc = nu_b[lane];
  for (int k = 0; k < 32; k++) acc += xr[k] * nu_w[k * 64 + lane];
  for (int k = 0; k < 64; k++) acc += crf[k] * nu_w[(32 + k) * 64 + lane];
  float h = fmaxf(acc, 0.f);
  float mu = wredsum(h) * 0.015625f;
  float d = h - mu;
  float var = wredsum(d * d) * 0.015625f;
  node[(size_t)n * 64 + lane] = d * rsqrtf(var + LN_EPS) * nu_g[lane] + nu_be[lane];
}

// ---------------- edge encoder: LN(relu(edge_attr @ eu_w + eu_b)) ----------------

__global__ __launch_bounds__(256) void encode_edges_kernel(
    const float* __restrict__ ea, const float* __restrict__ eu_w, const float* __restrict__ eu_b,
    const float* __restrict__ eu_g, const float* __restrict__ eu_be, float* __restrict__ ef) {
  const int lane = threadIdx.x & 63, wv = threadIdx.x >> 6;
  const int e = blockIdx.x * 4 + wv;
  const float* er = ea + (size_t)e * 6;
  float acc = eu_b[lane];
#pragma unroll
  for (int k = 0; k < 6; k++) acc += er[k] * eu_w[k * 64 + lane];
  float h = fmaxf(acc, 0.f);
  float mu = wredsum(h) * 0.015625f;
  float d = h - mu;
  float var = wredsum(d * d) * 0.015625f;
  ef[(size_t)e * 64 + lane] = d * rsqrtf(var + LN_EPS) * eu_g[lane] + eu_be[lane];
}

// ---------------- message + scatter-add: msg = relu([node[dst],node[src],edge]@w1+b1)@w2+b2 ----------------

__global__ __launch_bounds__(256) void message_kernel(
    const float* __restrict__ node, const float* __restrict__ ef, const int* __restrict__ ei,
    const float* __restrict__ w1, const float* __restrict__ b1, const float* __restrict__ w2,
    const float* __restrict__ b2, float* __restrict__ agg) {
  __shared__ float s_w[12288];  // w1 [192][64]
  for (int i = threadIdx.x; i < 12288; i += 256) s_w[i] = w1[i];
  __syncthreads();
  const int lane = threadIdx.x & 63, wv = threadIdx.x >> 6;
  const int e0 = blockIdx.x * 32 + wv * 8;
  const int* srcp = ei;
  const int* dstp = ei + NE;
  const float* rD[8];
  const float* rS[8];
  const float* rE[8];
  int dd[8];
#pragma unroll
  for (int i = 0; i < 8; i++) {
    int e = e0 + i;
    int s = __builtin_amdgcn_readfirstlane(srcp[e]);
    int d = __builtin_amdgcn_readfirstlane(dstp[e]);
    dd[i] = d;
    rD[i] = node + (size_t)d * 64;
    rS[i] = node + (size_t)s * 64;
    rE[i] = ef + (size_t)e * 64;
  }
  float acc[8];
  const float bb = b1[lane];
#pragma unroll
  for (int i = 0; i < 8; i++) acc[i] = bb;
  for (int k = 0; k < 64; k++) {
    float w = s_w[k * 64 + lane];
#pragma unroll
    for (int i = 0; i < 8; i++) acc[i] += rD[i][k] * w;
  }
  for (int k = 0; k < 64; k++) {
    float w = s_w[(64 + k) * 64 + lane];
#pragma unroll
    for (int i = 0; i < 8; i++) acc[i] += rS[i][k] * w;
  }
  for (int k = 0; k < 64; k++) {
    float w = s_w[(128 + k) * 64 + lane];
#pragma unroll
    for (int i = 0; i < 8; i++) acc[i] += rE[i][k] * w;
  }
  float h[8];
#pragma unroll
  for (int i = 0; i < 8; i++) h[i] = fmaxf(acc[i], 0.f);
  float m[8];
  const float b2v = b2[lane];
#pragma unroll
  for (int i = 0; i < 8; i++) m[i] = b2v;
  for (int k = 0; k < 64; k++) {
    float w = w2[k * 64 + lane];
#pragma unroll
    for (int i = 0; i < 8; i++) m[i] += __shfl(h[i], k, 64) * w;
  }
#pragma unroll
  for (int i = 0; i < 8; i++) atomicAdd(agg + (size_t)dd[i] * 64 + lane, m[i]);
}

// ---------------- node update: relu([node,agg]@w1+b1)@w2+b2 ----------------

__global__ __launch_bounds__(256) void node_update_kernel(
    const float* __restrict__ node, const float* __restrict__ agg, const float* __restrict__ w1,
    const float* __restrict__ b1, const float* __restrict__ w2, const float* __restrict__ b2,
    float* __restrict__ out) {
  __shared__ float s_w[8192];  // w1 [128][64]
  for (int i = threadIdx.x; i < 8192; i += 256) s_w[i] = w1[i];
  __syncthreads();
  const int lane = threadIdx.x & 63, wv = threadIdx.x >> 6;
  const int n0 = blockIdx.x * 32 + wv * 8;
  const float* rN[8];
  const float* rA[8];
  float acc[8];
  const float bb = b1[lane];
#pragma unroll
  for (int i = 0; i < 8; i++) {
    int n = (n0 + i < NN) ? (n0 + i) : 0;
    rN[i] = node + (size_t)n * 64;
    rA[i] = agg + (size_t)n * 64;
    acc[i] = bb;
  }
  for (int k = 0; k < 64; k++) {
    float w = s_w[k * 64 + lane];
#pragma unroll
    for (int i = 0; i < 8; i++) acc[i] += rN[i][k] * w;
  }
  for (int k = 0; k < 64; k++) {
    float w = s_w[(64 + k) * 64 + lane];
#pragma unroll
    for (int i = 0; i < 8; i++) acc[i] += rA[i][k] * w;
  }
  float h[8];
#pragma unroll
  for (int i = 0; i < 8; i++) h[i] = fmaxf(acc[i], 0.f);
  float m[8];
  const float b2v = b2[lane];
#pragma unroll
  for (int i = 0; i < 8; i++) m[i] = b2v;
  for (int k = 0; k < 64; k++) {
    float w = w2[k * 64 + lane];
#pragma unroll
    for (int i = 0; i < 8; i++) m[i] += __shfl(h[i], k, 64) * w;
  }
#pragma unroll
  for (int i = 0; i < 8; i++)
    if (n0 + i < NN) out[(size_t)(n0 + i) * 64 + lane] = m[i];
}

// ---------------- final edge MLP: [node[src],node[dst],edge_attr] -> 128 -> 64 -> 1 ----------------

__global__ __launch_bounds__(256) void final_mlp_kernel(
    const float* __restrict__ node, const float* __restrict__ ea, const int* __restrict__ ei,
    const float* __restrict__ w1, const float* __restrict__ b1, const float* __restrict__ w2,
    const float* __restrict__ b2, const float* __restrict__ w3, const float* __restrict__ b3,
    float* __restrict__ out) {
  __shared__ float s_w[8576];  // max(134*64, 128*64)
  const int lane = threadIdx.x & 63, wv = threadIdx.x >> 6;
  const int e0 = blockIdx.x * 32 + wv * 8;
  const int* srcp = ei;
  const int* dstp = ei + NE;
  const float* rS[8];
  const float* rD[8];
  const float* rA[8];
  int ee[8];
#pragma unroll
  for (int i = 0; i < 8; i++) {
    int e = e0 + i;
    ee[i] = e;
    int s = __builtin_amdgcn_readfirstlane(srcp[e]);
    int d = __builtin_amdgcn_readfirstlane(dstp[e]);
    rS[i] = node + (size_t)s * 64;  // src FIRST here
    rD[i] = node + (size_t)d * 64;
    rA[i] = ea + (size_t)e * 6;
  }
  // stage em_w1 cols 0..63
  for (int i = threadIdx.x; i < 8576; i += 256) s_w[i] = w1[(i >> 6) * 128 + (i & 63)];
  __syncthreads();
  float h1a[8];
  {
    float acc[8];
    const float bb = b1[lane];
#pragma unroll
    for (int i = 0; i < 8; i++) acc[i] = bb;
    for (int k = 0; k < 64; k++) {
      float w = s_w[k * 64 + lane];
#pragma unroll
      for (int i = 0; i < 8; i++) acc[i] += rS[i][k] * w;
    }
    for (int k = 0; k < 64; k++) {
      float w = s_w[(64 + k) * 64 + lane];
#pragma unroll
      for (int i = 0; i < 8; i++) acc[i] += rD[i][k] * w;
    }
#pragma unroll
    for (int k = 0; k < 6; k++) {
      float w = s_w[(128 + k) * 64 + lane];
#pragma unroll
      for (int i = 0; i < 8; i++) acc[i] += rA[i][k] * w;
    }
#pragma unroll
    for (int i = 0; i < 8; i++) h1a[i] = fmaxf(acc[i], 0.f);
  }
  __syncthreads();
  // stage em_w1 cols 64..127
  for (int i = threadIdx.x; i < 8576; i += 256) s_w[i] = w1[(i >> 6) * 128 + 64 + (i & 63)];
  __syncthreads();
  float h1b[8];
  {
    float acc[8];
    const float bb = b1[64 + lane];
#pragma unroll
    for (int i = 0; i < 8; i++) acc[i] = bb;
    for (int k = 0; k < 64; k++) {
      float w = s_w[k * 64 + lane];
#pragma unroll
      for (int i = 0; i < 8; i++) acc[i] += rS[i][k] * w;
    }
    for (int k = 0; k < 64; k++) {
      float w = s_w[(64 + k) * 64 + lane];
#pragma unroll
      for (int i = 0; i < 8; i++) acc[i] += rD[i][k] * w;
    }
#pragma unroll
    for (int k = 0; k < 6; k++) {
      float w = s_w[(128 + k) * 64 + lane];
#pragma unroll
      for (int i = 0; i < 8; i++) acc[i] += rA[i][k] * w;
    }
#pragma unroll
    for (int i = 0; i < 8; i++) h1b[i] = fmaxf(acc[i], 0.f);
  }
  __syncthreads();
  // stage em_w2 [128][64]
  for (int i = threadIdx.x; i < 8192; i += 256) s_w[i] = w2[i];
  __syncthreads();
  float h2[8];
  {
    float acc[8];
    const float bb = b2[lane];
#pragma unroll
    for (int i = 0; i < 8; i++) acc[i] = bb;
    for (int k = 0; k < 64; k++) {
      float w = s_w[k * 64 + lane];
#pragma unroll
      for (int i = 0; i < 8; i++) acc[i] += __shfl(h1a[i], k, 64) * w;
    }
    for (int k = 0; k < 64; k++) {
      float w = s_w[(64 + k) * 64 + lane];
#pragma unroll
      for (int i = 0; i < 8; i++) acc[i] += __shfl(h1b[i], k, 64) * w;
    }
#pragma unroll
    for (int i = 0; i < 8; i++) h2[i] = fmaxf(acc[i], 0.f);
  }
  const float w3v = w3[lane];
  const float b3v = b3[0];
#pragma unroll
  for (int i = 0; i < 8; i++) {
    float v = wredsum(h2[i] * w3v);
    if (lane == 0) out[ee[i]] = v + b3v;
  }
}

// ---------------- launch ----------------

extern "C" void kernel_launch(void* const* d_in, const int* in_sizes, int n_in, void* d_out,
                              int out_size, void* d_ws, size_t ws_size, hipStream_t stream) {
  const float* x = (const float*)d_in[0];
  const int* ei = (const int*)d_in[1];
  const float* ea = (const float*)d_in[2];
  const float* crop = (const float*)d_in[3];
  const float* cw0 = (const float*)d_in[4];
  const float* cb0 = (const float*)d_in[5];
  const float* cw = (const float*)d_in[6];
  const float* cb = (const float*)d_in[7];
  const float* nu_w = (const float*)d_in[8];
  const float* nu_b = (const float*)d_in[9];
  const float* nu_g = (const float*)d_in[10];
  const float* nu_be = (const float*)d_in[11];
  const float* eu_w = (const float*)d_in[12];
  const float* eu_b = (const float*)d_in[13];
  const float* eu_g = (const float*)d_in[14];
  const float* eu_be = (const float*)d_in[15];
  const float* ie_w1 = (const float*)d_in[16];
  const float* ie_b1 = (const float*)d_in[17];
  const float* ie_w2 = (const float*)d_in[18];
  const float* ie_b2 = (const float*)d_in[19];
  const float* in_w1 = (const float*)d_in[20];
  const float* in_b1 = (const float*)d_in[21];
  const float* in_w2 = (const float*)d_in[22];
  const float* in_b2 = (const float*)d_in[23];
  const float* em_w1 = (const float*)d_in[24];
  const float* em_b1 = (const float*)d_in[25];
  const float* em_w2 = (const float*)d_in[26];
  const float* em_b2 = (const float*)d_in[27];
  const float* em_w3 = (const float*)d_in[28];
  const float* em_b3 = (const float*)d_in[29];
  float* out = (float*)d_out;

  float* ws = (float*)d_ws;
  float* wt = ws;                         // 81920
  float* crop_feat = wt + 81920;          // 640000
  float* node_a = crop_feat + 640000;     // 640000
  float* node_b = node_a + 640000;        // 640000
  float* agg = node_b + 640000;           // 640000
  float* edge_f = agg + 640000;           // 20480000

  prep_weights_kernel<<<dim3(320), dim3(256), 0, stream>>>(cw, wt);
  conv_stack_kernel<<<dim3(NN), dim3(256), 0, stream>>>(crop, cw0, cb0, wt, cb, crop_feat);
  encode_nodes_kernel<<<dim3(NN / 4), dim3(256), 0, stream>>>(x, crop_feat, nu_w, nu_b, nu_g,
                                                              nu_be, node_a);
  encode_edges_kernel<<<dim3(NE / 4), dim3(256), 0, stream>>>(ea, eu_w, eu_b, eu_g, eu_be, edge_f);

  const float* ncur = node_a;
  float* nnext = node_b;
  for (int l = 0; l < 4; l++) {
    hipMemsetAsync(agg, 0, (size_t)640000 * sizeof(float), stream);
    message_kernel<<<dim3(NE / 32), dim3(256), 0, stream>>>(
        ncur, edge_f, ei, ie_w1 + (size_t)l * 12288, ie_b1 + l * 64, ie_w2 + (size_t)l * 4096,
        ie_b2 + l * 64, agg);
    node_update_kernel<<<dim3((NN + 31) / 32), dim3(256), 0, stream>>>(
        ncur, agg, in_w1 + (size_t)l * 8192, in_b1 + l * 64, in_w2 + (size_t)l * 4096,
        in_b2 + l * 64, nnext);
    float* tmp = (float*)ncur;
    ncur = nnext;
    nnext = tmp;
  }
  final_mlp_kernel<<<dim3(NE / 32), dim3(256), 0, stream>>>(ncur, ea, ei, em_w1, em_b1, em_w2,
                                                            em_b2, em_w3, em_b3, out);
}

// Round 2
// 3282.452 us; speedup vs baseline: 2.7557x; 2.7557x over previous
//
#include <hip/hip_runtime.h>
#include <cstdint>
#include <cstddef>

#define NN 10000
#define NE 320000
#define LN_EPS 1e-5f

typedef short bf16x8 __attribute__((ext_vector_type(8)));
typedef float f32x4 __attribute__((ext_vector_type(4)));

#define A0_STRIDE 40
#define A_STRIDE 264

// ---------------- helpers ----------------

__device__ __forceinline__ float wredsum(float v) {
#pragma unroll
  for (int off = 32; off > 0; off >>= 1) v += __shfl_xor(v, off, 64);
  return v;
}

__device__ __forceinline__ unsigned short f2bf(float x) {
  unsigned u = __float_as_uint(x);
  u = u + 0x7FFFu + ((u >> 16) & 1u);
  return (unsigned short)(u >> 16);
}

__device__ __forceinline__ unsigned packbf(float a, float b) {
  return (unsigned)f2bf(a) | ((unsigned)f2bf(b) << 16);
}

// ---------------- weight prep ----------------
// wt[5][256k][64co] fp32 (used by conv4/conv5 VALU path), k = ci*4+ky*2+kx
// wB bf16 MFMA B-fragments:
//   wB0  [4nt][64lane][8j]              (conv0, K=12 padded to 32, 1 kstep)
//   wB1/2/3 [8ks][4nt][64lane][8j]      (conv1..3, K=256)
// fragment value = W[k = ks*32 + (lane>>4)*8 + j][co = nt*16 + (lane&15)]

__global__ __launch_bounds__(256) void prep_weights_kernel(const float* __restrict__ cw0,
                                                           const float* __restrict__ cw,
                                                           float* __restrict__ wt,
                                                           unsigned short* __restrict__ wB) {
  int j = blockIdx.x * 256 + threadIdx.x;
  if (j < 5 * 16384) {
    int l = j >> 14;
    int rem = j & 16383;
    int k = rem >> 6;
    int co = rem & 63;
    wt[j] = cw[(size_t)((l << 6) + co) * 256 + k];
    return;
  }
  int g = j - 5 * 16384;
  if (g < 2048) {
    int nt = g >> 9, lane = (g >> 3) & 63, jj = g & 7;
    int k = ((lane >> 4) << 3) + jj;
    int co = nt * 16 + (lane & 15);
    float v = (k < 12) ? cw0[co * 12 + k] : 0.f;
    wB[g] = f2bf(v);
    return;
  }
  g -= 2048;
  if (g < 3 * 16384) {
    int l = g >> 14;  // 0..2 -> conv layers 1..3
    int r = g & 16383;
    int ks = r >> 11, nt = (r >> 9) & 3, lane = (r >> 3) & 63, jj = r & 7;
    int k = ks * 32 + ((lane >> 4) << 3) + jj;
    int co = nt * 16 + (lane & 15);
    wB[2048 + g] = f2bf(cw[(size_t)(((l << 6) + co) << 8) + k]);
  }
}

// ---------------- fused conv stack (MFMA): crop[N,3,64,64] -> crop_feat[N,64] ----------------
// s2d im2col at every stage: A[px][k], k = ci*4 + jy*2 + jx; GEMM out[px][co] = A @ W.
// conv0..conv3 via mfma_f32_16x16x32_bf16 (fp32 accum); conv4/conv5 tiny -> fp32 VALU.

__global__ __launch_bounds__(256) void conv_stack_kernel(
    const float* __restrict__ crop, const float* __restrict__ cb0,
    const unsigned short* __restrict__ wB, const float* __restrict__ wt,
    const float* __restrict__ cb, float* __restrict__ crop_feat) {
  // pool layout: [0,5120) A0 (64px x 40k bf16) ; [5120,13568) A1 (16 x 264) ;
  //              [13568,47360) A2 (64 x 264)
  // aliases: A3 (16 x 264) over A0/A1 ; s_o3(4KB)+s_o4(1KB)+s_red(1KB) over A2
  __shared__ __align__(16) char pool[47360];
  unsigned short* sA0 = (unsigned short*)pool;
  unsigned short* sA1 = (unsigned short*)(pool + 5120);
  unsigned short* sA2 = (unsigned short*)(pool + 13568);
  unsigned short* sA3 = (unsigned short*)pool;
  float* s_o3 = (float*)(pool + 13568);
  float* s_o4 = (float*)(pool + 17664);
  float* s_red = (float*)(pool + 18688);

  const int t = threadIdx.x;
  const int lane = t & 63, wv = t >> 6;
  const int col = lane & 15, quad = lane >> 4;
  const int n = blockIdx.x;
  const float* cr = crop + (size_t)n * 12288;
  const int co = wv * 16 + col;

  // zero A0 pad region k in [12,40)
  for (int i = t; i < 64 * 28; i += 256) {
    int px = i / 28, kk = 12 + i - px * 28;
    sA0[px * A0_STRIDE + kk] = 0;
  }

  // B fragments held in registers
  bf16x8 b0 = *(const bf16x8*)(wB + (wv * 64 + lane) * 8);
  bf16x8 b1f[8];
#pragma unroll
  for (int ks = 0; ks < 8; ks++)
    b1f[ks] = *(const bf16x8*)(wB + 2048 + ((ks * 4 + wv) * 64 + lane) * 8);

  const float bias0 = cb0[co];
  const float bias1 = cb[co];

  // strip prefetch: thread t -> input row r0 (of 4), col c0; 3 channels
  const int r0 = t >> 6, c0 = t & 63;
  const int a0base = ((r0 >> 1) * 32 + (c0 >> 1)) * A0_STRIDE + (r0 & 1) * 2 + (c0 & 1);
  float pf0 = cr[r0 * 64 + c0];
  float pf1 = cr[4096 + r0 * 64 + c0];
  float pf2 = cr[8192 + r0 * 64 + c0];

  for (int y1 = 0; y1 < 16; y1++) {
    // write strip to A0 (k = ci*4 + (r&1)*2 + (c&1))
    sA0[a0base + 0] = f2bf(pf0);
    sA0[a0base + 4] = f2bf(pf1);
    sA0[a0base + 8] = f2bf(pf2);
    __syncthreads();
    if (y1 < 15) {
      const float* base = cr + (4 * (y1 + 1) + r0) * 64 + c0;
      pf0 = base[0];
      pf1 = base[4096];
      pf2 = base[8192];
    }
    // conv0: 4 m-tiles (64 strip px), 1 kstep -> A1 strip [16px1][256k]
#pragma unroll
    for (int mt = 0; mt < 4; mt++) {
      f32x4 acc = {0.f, 0.f, 0.f, 0.f};
      bf16x8 a = *(const bf16x8*)(sA0 + (mt * 16 + col) * A0_STRIDE + quad * 8);
      acc = __builtin_amdgcn_mfma_f32_16x16x32_bf16(a, b0, acc, 0, 0, 0);
#pragma unroll
      for (int r = 0; r < 4; r += 2) {
        int px = mt * 16 + quad * 4 + r;
        int y = px >> 5, x = px & 31;
        float v0 = fmaxf(acc[r] + bias0, 0.f);
        float v1 = fmaxf(acc[r + 1] + bias0, 0.f);
        *(unsigned*)(sA1 + (x >> 1) * A_STRIDE + co * 4 + y * 2) = packbf(v0, v1);
      }
    }
    __syncthreads();
    // conv1: 1 m-tile (16 px of out1 row y1), 8 ksteps -> A2[64px2][256k]
    f32x4 acc1 = {0.f, 0.f, 0.f, 0.f};
#pragma unroll
    for (int ks = 0; ks < 8; ks++) {
      bf16x8 a = *(const bf16x8*)(sA1 + col * A_STRIDE + ks * 32 + quad * 8);
      acc1 = __builtin_amdgcn_mfma_f32_16x16x32_bf16(a, b1f[ks], acc1, 0, 0, 0);
    }
#pragma unroll
    for (int r = 0; r < 4; r += 2) {
      int x1 = quad * 4 + r;
      float v0 = fmaxf(acc1[r] + bias1, 0.f);
      float v1 = fmaxf(acc1[r + 1] + bias1, 0.f);
      *(unsigned*)(sA2 + ((y1 >> 1) * 8 + (x1 >> 1)) * A_STRIDE + co * 4 + (y1 & 1) * 2) =
          packbf(v0, v1);
    }
    __syncthreads();
  }

  // conv2: A2[64][256] -> A3[16][256]  (4 m-tiles x 8 ksteps)
  bf16x8 b2f[8], b3f[8];
#pragma unroll
  for (int ks = 0; ks < 8; ks++) {
    b2f[ks] = *(const bf16x8*)(wB + 18432 + ((ks * 4 + wv) * 64 + lane) * 8);
    b3f[ks] = *(const bf16x8*)(wB + 34816 + ((ks * 4 + wv) * 64 + lane) * 8);
  }
  const float bias2 = cb[64 + co];
  f32x4 a2acc[4];
#pragma unroll
  for (int mt = 0; mt < 4; mt++) {
    f32x4 acc = {0.f, 0.f, 0.f, 0.f};
#pragma unroll
    for (int ks = 0; ks < 8; ks++) {
      bf16x8 a = *(const bf16x8*)(sA2 + (mt * 16 + col) * A_STRIDE + ks * 32 + quad * 8);
      acc = __builtin_amdgcn_mfma_f32_16x16x32_bf16(a, b2f[ks], acc, 0, 0, 0);
    }
    a2acc[mt] = acc;
  }
  __syncthreads();  // all conv2 reads of A2 done; A3 region (over A0/A1) now writable
#pragma unroll
  for (int mt = 0; mt < 4; mt++) {
#pragma unroll
    for (int r = 0; r < 4; r += 2) {
      int px2 = mt * 16 + quad * 4 + r;
      int y2 = px2 >> 3, x2 = px2 & 7;
      float v0 = fmaxf(a2acc[mt][r] + bias2, 0.f);
      float v1 = fmaxf(a2acc[mt][r + 1] + bias2, 0.f);
      *(unsigned*)(sA3 + ((y2 >> 1) * 4 + (x2 >> 1)) * A_STRIDE + co * 4 + (y2 & 1) * 2) =
          packbf(v0, v1);
    }
  }
  __syncthreads();

  // conv3: A3[16][256] -> s_o3 fp32 [256k][4px]  (1 m-tile x 8 ksteps)
  const float bias3 = cb[128 + co];
  {
    f32x4 acc = {0.f, 0.f, 0.f, 0.f};
#pragma unroll
    for (int ks = 0; ks < 8; ks++) {
      bf16x8 a = *(const bf16x8*)(sA3 + col * A_STRIDE + ks * 32 + quad * 8);
      acc = __builtin_amdgcn_mfma_f32_16x16x32_bf16(a, b3f[ks], acc, 0, 0, 0);
    }
    __syncthreads();  // conv3 reads done... and A2 (s_o3 alias) fully dead
#pragma unroll
    for (int r = 0; r < 4; r++) {
      int px3 = quad * 4 + r;
      int y3 = px3 >> 2, x3 = px3 & 3;
      s_o3[(co * 4 + (y3 & 1) * 2 + (x3 & 1)) * 4 + (y3 >> 1) * 2 + (x3 >> 1)] =
          fmaxf(acc[r] + bias3, 0.f);
    }
  }
  __syncthreads();

  // conv4: out4[64][2][2], fp32 VALU
  {
    const int p4 = t & 3, co4 = t >> 2;
    float a4 = 0.f;
    const float* w4p = wt + 3 * 16384 + co4;
    for (int k = 0; k < 256; k++) a4 += s_o3[k * 4 + p4] * w4p[k * 64];
    s_o4[co4 * 4 + p4] = fmaxf(a4 + cb[192 + co4], 0.f);
  }
  __syncthreads();

  // conv5: out5[64], fp32 VALU, split K over 4 groups
  {
    const int co5 = t & 63, ks = t >> 6;
    float p = 0.f;
    const float* w5p = wt + 4 * 16384 + co5;
    for (int kk = 0; kk < 64; kk++) {
      int k = ks * 64 + kk;
      p += s_o4[k] * w5p[k * 64];
    }
    s_red[t] = p;
  }
  __syncthreads();
  if (t < 64) {
    float v = s_red[t] + s_red[64 + t] + s_red[128 + t] + s_red[192 + t];
    crop_feat[(size_t)n * 64 + t] = fmaxf(v + cb[256 + t], 0.f);
  }
}

// ---------------- node encoder: LN(relu([x, crop_feat] @ nu_w + nu_b)) ----------------

__global__ __launch_bounds__(256) void encode_nodes_kernel(
    const float* __restrict__ x, const float* __restrict__ cf, const float* __restrict__ nu_w,
    const float* __restrict__ nu_b, const float* __restrict__ nu_g, const float* __restrict__ nu_be,
    float* __restrict__ node) {
  const int lane = threadIdx.x & 63, wv = threadIdx.x >> 6;
  const int n = blockIdx.x * 4 + wv;
  const float* xr = x + (size_t)n * 32;
  const float* crf = cf + (size_t)n * 64;
  float acc = nu_b[lane];
  for (int k = 0; k < 32; k++) acc += xr[k] * nu_w[k * 64 + lane];
  for (int k = 0; k < 64; k++) acc += crf[k] * nu_w[(32 + k) * 64 + lane];
  float h = fmaxf(acc, 0.f);
  float mu = wredsum(h) * 0.015625f;
  float d = h - mu;
  float var = wredsum(d * d) * 0.015625f;
  node[(size_t)n * 64 + lane] = d * rsqrtf(var + LN_EPS) * nu_g[lane] + nu_be[lane];
}

// ---------------- edge encoder: LN(relu(edge_attr @ eu_w + eu_b)) ----------------

__global__ __launch_bounds__(256) void encode_edges_kernel(
    const float* __restrict__ ea, const float* __restrict__ eu_w, const float* __restrict__ eu_b,
    const float* __restrict__ eu_g, const float* __restrict__ eu_be, float* __restrict__ ef) {
  const int lane = threadIdx.x & 63, wv = threadIdx.x >> 6;
  const int e = blockIdx.x * 4 + wv;
  const float* er = ea + (size_t)e * 6;
  float acc = eu_b[lane];
#pragma unroll
  for (int k = 0; k < 6; k++) acc += er[k] * eu_w[k * 64 + lane];
  float h = fmaxf(acc, 0.f);
  float mu = wredsum(h) * 0.015625f;
  float d = h - mu;
  float var = wredsum(d * d) * 0.015625f;
  ef[(size_t)e * 64 + lane] = d * rsqrtf(var + LN_EPS) * eu_g[lane] + eu_be[lane];
}

// ---------------- message + scatter-add ----------------

__global__ __launch_bounds__(256) void message_kernel(
    const float* __restrict__ node, const float* __restrict__ ef, const int* __restrict__ ei,
    const float* __restrict__ w1, const float* __restrict__ b1, const float* __restrict__ w2,
    const float* __restrict__ b2, float* __restrict__ agg) {
  __shared__ float s_w[12288];  // w1 [192][64]
  for (int i = threadIdx.x; i < 12288; i += 256) s_w[i] = w1[i];
  __syncthreads();
  const int lane = threadIdx.x & 63, wv = threadIdx.x >> 6;
  const int e0 = blockIdx.x * 32 + wv * 8;
  const int* srcp = ei;
  const int* dstp = ei + NE;
  const float* rD[8];
  const float* rS[8];
  const float* rE[8];
  int dd[8];
#pragma unroll
  for (int i = 0; i < 8; i++) {
    int e = e0 + i;
    int s = __builtin_amdgcn_readfirstlane(srcp[e]);
    int d = __builtin_amdgcn_readfirstlane(dstp[e]);
    dd[i] = d;
    rD[i] = node + (size_t)d * 64;
    rS[i] = node + (size_t)s * 64;
    rE[i] = ef + (size_t)e * 64;
  }
  float acc[8];
  const float bb = b1[lane];
#pragma unroll
  for (int i = 0; i < 8; i++) acc[i] = bb;
  for (int k = 0; k < 64; k++) {
    float w = s_w[k * 64 + lane];
#pragma unroll
    for (int i = 0; i < 8; i++) acc[i] += rD[i][k] * w;
  }
  for (int k = 0; k < 64; k++) {
    float w = s_w[(64 + k) * 64 + lane];
#pragma unroll
    for (int i = 0; i < 8; i++) acc[i] += rS[i][k] * w;
  }
  for (int k = 0; k < 64; k++) {
    float w = s_w[(128 + k) * 64 + lane];
#pragma unroll
    for (int i = 0; i < 8; i++) acc[i] += rE[i][k] * w;
  }
  float h[8];
#pragma unroll
  for (int i = 0; i < 8; i++) h[i] = fmaxf(acc[i], 0.f);
  float m[8];
  const float b2v = b2[lane];
#pragma unroll
  for (int i = 0; i < 8; i++) m[i] = b2v;
  for (int k = 0; k < 64; k++) {
    float w = w2[k * 64 + lane];
#pragma unroll
    for (int i = 0; i < 8; i++) m[i] += __shfl(h[i], k, 64) * w;
  }
#pragma unroll
  for (int i = 0; i < 8; i++) atomicAdd(agg + (size_t)dd[i] * 64 + lane, m[i]);
}

// ---------------- node update ----------------

__global__ __launch_bounds__(256) void node_update_kernel(
    const float* __restrict__ node, const float* __restrict__ agg, const float* __restrict__ w1,
    const float* __restrict__ b1, const float* __restrict__ w2, const float* __restrict__ b2,
    float* __restrict__ out) {
  __shared__ float s_w[8192];  // w1 [128][64]
  for (int i = threadIdx.x; i < 8192; i += 256) s_w[i] = w1[i];
  __syncthreads();
  const int lane = threadIdx.x & 63, wv = threadIdx.x >> 6;
  const int n0 = blockIdx.x * 32 + wv * 8;
  const float* rN[8];
  const float* rA[8];
  float acc[8];
  const float bb = b1[lane];
#pragma unroll
  for (int i = 0; i < 8; i++) {
    int n = (n0 + i < NN) ? (n0 + i) : 0;
    rN[i] = node + (size_t)n * 64;
    rA[i] = agg + (size_t)n * 64;
    acc[i] = bb;
  }
  for (int k = 0; k < 64; k++) {
    float w = s_w[k * 64 + lane];
#pragma unroll
    for (int i = 0; i < 8; i++) acc[i] += rN[i][k] * w;
  }
  for (int k = 0; k < 64; k++) {
    float w = s_w[(64 + k) * 64 + lane];
#pragma unroll
    for (int i = 0; i < 8; i++) acc[i] += rA[i][k] * w;
  }
  float h[8];
#pragma unroll
  for (int i = 0; i < 8; i++) h[i] = fmaxf(acc[i], 0.f);
  float m[8];
  const float b2v = b2[lane];
#pragma unroll
  for (int i = 0; i < 8; i++) m[i] = b2v;
  for (int k = 0; k < 64; k++) {
    float w = w2[k * 64 + lane];
#pragma unroll
    for (int i = 0; i < 8; i++) m[i] += __shfl(h[i], k, 64) * w;
  }
#pragma unroll
  for (int i = 0; i < 8; i++)
    if (n0 + i < NN) out[(size_t)(n0 + i) * 64 + lane] = m[i];
}

// ---------------- final edge MLP ----------------

__global__ __launch_bounds__(256) void final_mlp_kernel(
    const float* __restrict__ node, const float* __restrict__ ea, const int* __restrict__ ei,
    const float* __restrict__ w1, const float* __restrict__ b1, const float* __restrict__ w2,
    const float* __restrict__ b2, const float* __restrict__ w3, const float* __restrict__ b3,
    float* __restrict__ out) {
  __shared__ float s_w[8576];  // max(134*64, 128*64)
  const int lane = threadIdx.x & 63, wv = threadIdx.x >> 6;
  const int e0 = blockIdx.x * 32 + wv * 8;
  const int* srcp = ei;
  const int* dstp = ei + NE;
  const float* rS[8];
  const float* rD[8];
  const float* rA[8];
  int ee[8];
#pragma unroll
  for (int i = 0; i < 8; i++) {
    int e = e0 + i;
    ee[i] = e;
    int s = __builtin_amdgcn_readfirstlane(srcp[e]);
    int d = __builtin_amdgcn_readfirstlane(dstp[e]);
    rS[i] = node + (size_t)s * 64;
    rD[i] = node + (size_t)d * 64;
    rA[i] = ea + (size_t)e * 6;
  }
  for (int i = threadIdx.x; i < 8576; i += 256) s_w[i] = w1[(i >> 6) * 128 + (i & 63)];
  __syncthreads();
  float h1a[8];
  {
    float acc[8];
    const float bb = b1[lane];
#pragma unroll
    for (int i = 0; i < 8; i++) acc[i] = bb;
    for (int k = 0; k < 64; k++) {
      float w = s_w[k * 64 + lane];
#pragma unroll
      for (int i = 0; i < 8; i++) acc[i] += rS[i][k] * w;
    }
    for (int k = 0; k < 64; k++) {
      float w = s_w[(64 + k) * 64 + lane];
#pragma unroll
      for (int i = 0; i < 8; i++) acc[i] += rD[i][k] * w;
    }
#pragma unroll
    for (int k = 0; k < 6; k++) {
      float w = s_w[(128 + k) * 64 + lane];
#pragma unroll
      for (int i = 0; i < 8; i++) acc[i] += rA[i][k] * w;
    }
#pragma unroll
    for (int i = 0; i < 8; i++) h1a[i] = fmaxf(acc[i], 0.f);
  }
  __syncthreads();
  for (int i = threadIdx.x; i < 8576; i += 256) s_w[i] = w1[(i >> 6) * 128 + 64 + (i & 63)];
  __syncthreads();
  float h1b[8];
  {
    float acc[8];
    const float bb = b1[64 + lane];
#pragma unroll
    for (int i = 0; i < 8; i++) acc[i] = bb;
    for (int k = 0; k < 64; k++) {
      float w = s_w[k * 64 + lane];
#pragma unroll
      for (int i = 0; i < 8; i++) acc[i] += rS[i][k] * w;
    }
    for (int k = 0; k < 64; k++) {
      float w = s_w[(64 + k) * 64 + lane];
#pragma unroll
      for (int i = 0; i < 8; i++) acc[i] += rD[i][k] * w;
    }
#pragma unroll
    for (int k = 0; k < 6; k++) {
      float w = s_w[(128 + k) * 64 + lane];
#pragma unroll
      for (int i = 0; i < 8; i++) acc[i] += rA[i][k] * w;
    }
#pragma unroll
    for (int i = 0; i < 8; i++) h1b[i] = fmaxf(acc[i], 0.f);
  }
  __syncthreads();
  for (int i = threadIdx.x; i < 8192; i += 256) s_w[i] = w2[i];
  __syncthreads();
  float h2[8];
  {
    float acc[8];
    const float bb = b2[lane];
#pragma unroll
    for (int i = 0; i < 8; i++) acc[i] = bb;
    for (int k = 0; k < 64; k++) {
      float w = s_w[k * 64 + lane];
#pragma unroll
      for (int i = 0; i < 8; i++) acc[i] += __shfl(h1a[i], k, 64) * w;
    }
    for (int k = 0; k < 64; k++) {
      float w = s_w[(64 + k) * 64 + lane];
#pragma unroll
      for (int i = 0; i < 8; i++) acc[i] += __shfl(h1b[i], k, 64) * w;
    }
#pragma unroll
    for (int i = 0; i < 8; i++) h2[i] = fmaxf(acc[i], 0.f);
  }
  const float w3v = w3[lane];
  const float b3v = b3[0];
#pragma unroll
  for (int i = 0; i < 8; i++) {
    float v = wredsum(h2[i] * w3v);
    if (lane == 0) out[ee[i]] = v + b3v;
  }
}

// ---------------- launch ----------------

extern "C" void kernel_launch(void* const* d_in, const int* in_sizes, int n_in, void* d_out,
                              int out_size, void* d_ws, size_t ws_size, hipStream_t stream) {
  const float* x = (const float*)d_in[0];
  const int* ei = (const int*)d_in[1];
  const float* ea = (const float*)d_in[2];
  const float* crop = (const float*)d_in[3];
  const float* cw0 = (const float*)d_in[4];
  const float* cb0 = (const float*)d_in[5];
  const float* cw = (const float*)d_in[6];
  const float* cb = (const float*)d_in[7];
  const float* nu_w = (const float*)d_in[8];
  const float* nu_b = (const float*)d_in[9];
  const float* nu_g = (const float*)d_in[10];
  const float* nu_be = (const float*)d_in[11];
  const float* eu_w = (const float*)d_in[12];
  const float* eu_b = (const float*)d_in[13];
  const float* eu_g = (const float*)d_in[14];
  const float* eu_be = (const float*)d_in[15];
  const float* ie_w1 = (const float*)d_in[16];
  const float* ie_b1 = (const float*)d_in[17];
  const float* ie_w2 = (const float*)d_in[18];
  const float* ie_b2 = (const float*)d_in[19];
  const float* in_w1 = (const float*)d_in[20];
  const float* in_b1 = (const float*)d_in[21];
  const float* in_w2 = (const float*)d_in[22];
  const float* in_b2 = (const float*)d_in[23];
  const float* em_w1 = (const float*)d_in[24];
  const float* em_b1 = (const float*)d_in[25];
  const float* em_w2 = (const float*)d_in[26];
  const float* em_b2 = (const float*)d_in[27];
  const float* em_w3 = (const float*)d_in[28];
  const float* em_b3 = (const float*)d_in[29];
  float* out = (float*)d_out;

  float* ws = (float*)d_ws;
  float* wt = ws;                                  // 81920 f
  unsigned short* wB = (unsigned short*)(ws + 81920);  // 51200 bf16 (25600 f)
  float* crop_feat = ws + 81920 + 25600;           // 640000
  float* node_a = crop_feat + 640000;
  float* node_b = node_a + 640000;
  float* agg = node_b + 640000;
  float* edge_f = agg + 640000;                    // NE*64

  prep_weights_kernel<<<dim3(520), dim3(256), 0, stream>>>(cw0, cw, wt, wB);
  conv_stack_kernel<<<dim3(NN), dim3(256), 0, stream>>>(crop, cb0, wB, wt, cb, crop_feat);
  encode_nodes_kernel<<<dim3(NN / 4), dim3(256), 0, stream>>>(x, crop_feat, nu_w, nu_b, nu_g,
                                                              nu_be, node_a);
  encode_edges_kernel<<<dim3(NE / 4), dim3(256), 0, stream>>>(ea, eu_w, eu_b, eu_g, eu_be, edge_f);

  const float* ncur = node_a;
  float* nnext = node_b;
  for (int l = 0; l < 4; l++) {
    hipMemsetAsync(agg, 0, (size_t)640000 * sizeof(float), stream);
    message_kernel<<<dim3(NE / 32), dim3(256), 0, stream>>>(
        ncur, edge_f, ei, ie_w1 + (size_t)l * 12288, ie_b1 + l * 64, ie_w2 + (size_t)l * 4096,
        ie_b2 + l * 64, agg);
    node_update_kernel<<<dim3((NN + 31) / 32), dim3(256), 0, stream>>>(
        ncur, agg, in_w1 + (size_t)l * 8192, in_b1 + l * 64, in_w2 + (size_t)l * 4096,
        in_b2 + l * 64, nnext);
    float* tmp = (float*)ncur;
    ncur = nnext;
    nnext = tmp;
  }
  final_mlp_kernel<<<dim3(NE / 32), dim3(256), 0, stream>>>(ncur, ea, ei, em_w1, em_b1, em_w2,
                                                            em_b2, em_w3, em_b3, out);
}